// Round 13
// baseline (311.784 us; speedup 1.0000x reference)
//
#include <hip/hip_runtime.h>

typedef float f32x4 __attribute__((ext_vector_type(4)));
typedef _Float16 f16x8 __attribute__((ext_vector_type(8)));
typedef _Float16 f16x4 __attribute__((ext_vector_type(4)));

#define NSEQ 2048
#define KVBLK 64
#define NITER (NSEQ / KVBLK)        // 32
#define KFBYTES (KVBLK * 384)       // 24576 = 6*4096  (64 keys x 192 dims f16)
#define VTBYTES (288 * 2 * KVBLK)   // 36864  (288 dims x 64 keys f16, linear)
#define TILEB (KFBYTES + VTBYTES)   // 61440
#define KFOFF 0
#define VTOFF KFBYTES
#define PSTRIDE 72                  // f16 per P row (64 + 8 pad) -> 144B
#define WS_NEED (16ull * NITER * TILEB)   // 31,457,280 B

#define SCALE_L2E 0.10411754f       // log2(e)/sqrt(192): softmax in exp2 domain
#define DEFER_THR 11.0f             // defer-max threshold (log2 units); P <= 2^11 ok in f16

__device__ __forceinline__ void async_copy16(const void* g, void* l) {
    __builtin_amdgcn_global_load_lds((const __attribute__((address_space(1))) unsigned int*)g,
                                     (__attribute__((address_space(3))) unsigned int*)l, 16, 0, 0);
}

// ---------------- pre-pass: k features, f16, swizzled tile ----------------
// tile (head,kt): logical (j in [0,64), d in [0,192)) at byte (j*384 + d*2) ^ ((j&7)<<4)
__global__ __launch_bounds__(256)
void prep_kf(const float* __restrict__ k_mv, const float* __restrict__ k_s,
             unsigned char* __restrict__ ws)
{
    constexpr int IPIDX[8] = {0, 2, 3, 4, 8, 9, 10, 14};
    const int head = blockIdx.x >> 5, kt = blockIdx.x & 31;
    unsigned char* tb = ws + (size_t)(head * NITER + kt) * TILEB + KFOFF;
    const int tid = threadIdx.x;
    #pragma unroll
    for (int rep = 0; rep < 6; ++rep) {
        const int t = rep * 256 + tid;
        const int j = t & 63, oct = t >> 6;           // oct in [0,24)
        const size_t row = (size_t)head * NSEQ + kt * KVBLK + j;
        float v[8];
        if (oct < 16) {                                // IP gather, cmv = oct
            const float* p = k_mv + (row * 16 + oct) * 16;
            #pragma unroll
            for (int i = 0; i < 8; ++i) v[i] = p[IPIDX[i]];
        } else if (oct < 20) {                         // normalizer(k_s)
            const f32x4* p4 = (const f32x4*)(k_s + row * 32 + (oct - 16) * 8);
            f32x4 a = p4[0], b = p4[1];
            #pragma unroll
            for (int i = 0; i < 8; ++i) {
                float x = (i < 4) ? a[i & 3] : b[i & 3];
                v[i] = x / (x * x + 1e-3f);
            }
        } else {                                       // plain k_s
            const f32x4* p4 = (const f32x4*)(k_s + row * 32 + (oct - 20) * 8);
            f32x4 a = p4[0], b = p4[1];
            #pragma unroll
            for (int i = 0; i < 8; ++i) v[i] = (i < 4) ? a[i & 3] : b[i & 3];
        }
        f16x8 o;
        #pragma unroll
        for (int i = 0; i < 8; ++i) o[i] = (_Float16)v[i];
        *(f16x8*)(tb + ((j * 384 + oct * 16) ^ ((j & 7) << 4))) = o;
    }
}

// ---------------- pre-pass: V^T, f16, LINEAR tile (read via L1/L2, not LDS) ----------------
// tile (head,kt): logical (d in [0,288), j in [0,64)) at byte d*128 + j*2
__global__ __launch_bounds__(256)
void prep_vt(const float* __restrict__ v_mv, const float* __restrict__ v_s,
             unsigned char* __restrict__ ws)
{
    const int head = blockIdx.x >> 5, kt = blockIdx.x & 31;
    unsigned char* tb = ws + (size_t)(head * NITER + kt) * TILEB + VTOFF;
    const int tid = threadIdx.x;
    const size_t row0 = (size_t)head * NSEQ + kt * KVBLK;
    {
        const int d = tid;                             // 0..255 from v_mv
        float val[KVBLK];
        #pragma unroll
        for (int j = 0; j < KVBLK; ++j) val[j] = v_mv[(row0 + j) * 256 + d];
        #pragma unroll
        for (int jg = 0; jg < 8; ++jg) {
            f16x8 o;
            #pragma unroll
            for (int i = 0; i < 8; ++i) o[i] = (_Float16)val[jg * 8 + i];
            *(f16x8*)(tb + d * 128 + jg * 16) = o;
        }
    }
    if (tid < 32) {                                    // d = 256..287 from v_s
        const int d = 256 + tid;
        float val[KVBLK];
        #pragma unroll
        for (int j = 0; j < KVBLK; ++j) val[j] = v_s[(row0 + j) * 32 + tid];
        #pragma unroll
        for (int jg = 0; jg < 8; ++jg) {
            f16x8 o;
            #pragma unroll
            for (int i = 0; i < 8; ++i) o[i] = (_Float16)val[jg * 8 + i];
            *(f16x8*)(tb + d * 128 + jg * 16) = o;
        }
    }
}

// ---- main: 512 blocks x 256 threads (4 waves), 2 de-phased blocks/CU.
// R11 structure, but V comes from GLOBAL (ws tile) straight into registers —
// LDS holds only kf (24KB) + P. DS traffic drops 62 -> 30 b128/wave-iter;
// V loads issued in 3 chunks of 12, latency hidden under S/softmax/PV. ----
__global__ __launch_bounds__(256, 2)
void geoattn_main(const float* __restrict__ q_mv, const float* __restrict__ q_s,
                  const float* __restrict__ logw, const unsigned char* __restrict__ ws,
                  float* __restrict__ out)
{
    constexpr int IPIDX[8] = {0, 2, 3, 4, 8, 9, 10, 14};
    __shared__ __align__(16) unsigned char lbuf[KFBYTES];        // kf only
    __shared__ __align__(16) _Float16 P_all[4][16 * PSTRIDE];    // per-wave private

    const int bid  = blockIdx.x;                       // 512 blocks
    const int head = (bid & 7) | ((bid >> 8) << 3);    // same-head blocks share an XCD
    const int qt   = (bid >> 3) & 31;
    const int h    = head & 7;

    const int tid  = threadIdx.x;
    const int w    = tid >> 6;       // 0..3
    const int lane = tid & 63;
    const int lr   = lane & 15;
    const int lg   = lane >> 4;

    const size_t rowbase = (size_t)head * NSEQ;
    const int q0 = qt * 64;
    const unsigned char* wsh = ws + (size_t)head * NITER * TILEB;

    // prologue: kf(0) DMA before the Q build
    #pragma unroll
    for (int c = 0; c < 6; ++c)
        async_copy16(wsh + KFOFF + c * 4096 + tid * 16, &lbuf[c * 4096 + tid * 16]);

    // ---- Q fragment for own 16 rows (B-operand: col=lr=q-row, k=lg*8+i+32c) ----
    f16x8 qf[6];
    {
        const int qrow = q0 + w * 16 + lr;
        const float* qmv = q_mv + (rowbase + qrow) * 256;
        const float* qs  = q_s  + (rowbase + qrow) * 32;
        #pragma unroll
        for (int c = 0; c < 4; ++c) {
            const int cmv = 4 * c + lg;
            const float wgt = __expf(logw[h * 16 + cmv]) * SCALE_L2E;
            const float* p = qmv + cmv * 16;
            #pragma unroll
            for (int i = 0; i < 8; ++i)
                qf[c][i] = (_Float16)(p[IPIDX[i]] * wgt);
        }
        const f32x4* p4 = (const f32x4*)(qs + lg * 8);
        f32x4 a = p4[0], b = p4[1];
        #pragma unroll
        for (int i = 0; i < 8; ++i) {
            float x = (i < 4) ? a[i & 3] : b[i & 3];
            qf[4][i] = (_Float16)(SCALE_L2E * x / (x * x + 1e-3f));
            qf[5][i] = (_Float16)(SCALE_L2E * x);
        }
    }

    f32x4 acc[18];                    // own 16 rows x 288 dims
    #pragma unroll
    for (int dt = 0; dt < 18; ++dt) acc[dt] = f32x4{0.f, 0.f, 0.f, 0.f};
    float mrun = -1e30f, lrun = 0.f;  // lane owns q-row (w*16 + lr)

    _Float16* pb = &P_all[w][0];

    for (int kt = 0; kt < NITER; ++kt) {
        // ---- top: kf(kt) DMA landed everywhere (V regs of kt-1 all consumed) ----
        asm volatile("s_waitcnt vmcnt(0)" ::: "memory");
        __builtin_amdgcn_s_barrier();
        asm volatile("" ::: "memory");

        const unsigned char* vtile = wsh + (size_t)kt * TILEB + VTOFF;

        // ---- issue V chunk A (dt 0..5) — lands during S ----
        f16x8 vA[6][2];
        #pragma unroll
        for (int dl = 0; dl < 6; ++dl) {
            const int d = dl * 16 + lr;
            vA[dl][0] = *(const f16x8*)(vtile + d * 128 + lg * 16);
            vA[dl][1] = *(const f16x8*)(vtile + d * 128 + 64 + lg * 16);
        }

        // ---- S^T = K Q : lane holds P-row of q-row lr across 4 key groups ----
        f32x4 sacc[4];
        #pragma unroll
        for (int jt = 0; jt < 4; ++jt) sacc[jt] = f32x4{0.f, 0.f, 0.f, 0.f};
        __builtin_amdgcn_s_setprio(1);
        #pragma unroll
        for (int jt = 0; jt < 4; ++jt) {
            const int j = jt * 16 + lr;                 // key row
            #pragma unroll
            for (int c = 0; c < 6; ++c) {
                f16x8 kf = *(const f16x8*)(lbuf + KFOFF +
                            ((j * 384 + c * 64 + lg * 16) ^ ((lr & 7) << 4)));
                sacc[jt] = __builtin_amdgcn_mfma_f32_16x16x32_f16(kf, qf[c], sacc[jt], 0, 0, 0);
            }
        }
        __builtin_amdgcn_s_setprio(0);

        // ---- kf region free -> start kf(kt+1) DMA; issue V chunk B ----
        asm volatile("s_waitcnt lgkmcnt(0)" ::: "memory");
        __builtin_amdgcn_s_barrier();
        asm volatile("" ::: "memory");
        if (kt < NITER - 1) {
            const unsigned char* src = wsh + (size_t)(kt + 1) * TILEB + KFOFF;
            #pragma unroll
            for (int c = 0; c < 6; ++c)
                async_copy16(src + c * 4096 + tid * 16, &lbuf[c * 4096 + tid * 16]);
        }
        f16x8 vB[6][2];
        #pragma unroll
        for (int dl = 0; dl < 6; ++dl) {
            const int d = (6 + dl) * 16 + lr;
            vB[dl][0] = *(const f16x8*)(vtile + d * 128 + lg * 16);
            vB[dl][1] = *(const f16x8*)(vtile + d * 128 + 64 + lg * 16);
        }

        // ---- softmax (exp2 domain, defer-max) for own 16 rows ----
        float mloc;
        {
            float t0 = fmaxf(fmaxf(sacc[0][0], sacc[0][1]), fmaxf(sacc[0][2], sacc[0][3]));
            #pragma unroll
            for (int jt = 1; jt < 4; ++jt) {
                float t1 = fmaxf(fmaxf(sacc[jt][0], sacc[jt][1]), fmaxf(sacc[jt][2], sacc[jt][3]));
                t0 = fmaxf(t0, t1);
            }
            t0 = fmaxf(t0, __shfl_xor(t0, 16));
            t0 = fmaxf(t0, __shfl_xor(t0, 32));
            mloc = t0;
        }
        const bool need = (mloc > mrun + DEFER_THR);
        const float mnew = need ? mloc : mrun;
        const float alpha = exp2f(mrun - mnew);         // 1.0 when !need; 0 on first tile
        mrun = mnew;
        if (__ballot(need)) {                           // rare: redistribute alpha to acc rows
            float ar[4];
            #pragma unroll
            for (int r = 0; r < 4; ++r) ar[r] = __shfl(alpha, lg * 4 + r, 16);
            #pragma unroll
            for (int dt = 0; dt < 18; ++dt)
                #pragma unroll
                for (int r = 0; r < 4; ++r) acc[dt][r] *= ar[r];
            lrun *= alpha;
        }
        float ps = 0.f;
        #pragma unroll
        for (int jt = 0; jt < 4; ++jt) {
            f16x4 pk;
            #pragma unroll
            for (int r = 0; r < 4; ++r) {
                const float p = exp2f(sacc[jt][r] - mrun);
                ps += p;
                pk[r] = (_Float16)p;
            }
            *(f16x4*)(&pb[lr * PSTRIDE + jt * 16 + lg * 4]) = pk;
        }
        ps += __shfl_xor(ps, 16);
        ps += __shfl_xor(ps, 32);
        lrun += ps;

        // ---- O += P V : P from own LDS, V from registers ----
        f16x8 pf0 = *(const f16x8*)(&pb[lr * PSTRIDE + lg * 8]);        // keys 0..31
        f16x8 pf1 = *(const f16x8*)(&pb[lr * PSTRIDE + 32 + lg * 8]);   // keys 32..63
        __builtin_amdgcn_s_setprio(1);
        #pragma unroll
        for (int dl = 0; dl < 6; ++dl) {                // PV-A (compiler waits vA)
            acc[dl] = __builtin_amdgcn_mfma_f32_16x16x32_f16(pf0, vA[dl][0], acc[dl], 0, 0, 0);
            acc[dl] = __builtin_amdgcn_mfma_f32_16x16x32_f16(pf1, vA[dl][1], acc[dl], 0, 0, 0);
        }
        __builtin_amdgcn_s_setprio(0);
        f16x8 vC[6][2];                                 // issue V chunk C (dt 12..17)
        #pragma unroll
        for (int dl = 0; dl < 6; ++dl) {
            const int d = (12 + dl) * 16 + lr;
            vC[dl][0] = *(const f16x8*)(vtile + d * 128 + lg * 16);
            vC[dl][1] = *(const f16x8*)(vtile + d * 128 + 64 + lg * 16);
        }
        __builtin_amdgcn_s_setprio(1);
        #pragma unroll
        for (int dl = 0; dl < 6; ++dl) {                // PV-B
            acc[6 + dl] = __builtin_amdgcn_mfma_f32_16x16x32_f16(pf0, vB[dl][0], acc[6 + dl], 0, 0, 0);
            acc[6 + dl] = __builtin_amdgcn_mfma_f32_16x16x32_f16(pf1, vB[dl][1], acc[6 + dl], 0, 0, 0);
        }
        #pragma unroll
        for (int dl = 0; dl < 6; ++dl) {                // PV-C
            acc[12 + dl] = __builtin_amdgcn_mfma_f32_16x16x32_f16(pf0, vC[dl][0], acc[12 + dl], 0, 0, 0);
            acc[12 + dl] = __builtin_amdgcn_mfma_f32_16x16x32_f16(pf1, vC[dl][1], acc[12 + dl], 0, 0, 0);
        }
        __builtin_amdgcn_s_setprio(0);
    }

    // ---- epilogue: out = acc / l (l redistributed in-wave; no cross-wave state) ----
    #pragma unroll
    for (int r = 0; r < 4; ++r) {
        const float lv = __shfl(lrun, lg * 4 + r, 16);
        const float inv = 1.0f / lv;
        const int row = q0 + w * 16 + lg * 4 + r;
        float* omv = out + (rowbase + row) * 256;
        float* os  = out + 8388608ull + (rowbase + row) * 32;
        #pragma unroll
        for (int dt = 0; dt < 18; ++dt) {
            const int d = dt * 16 + lr;
            const float val = acc[dt][r] * inv;
            if (d < 256) omv[d] = val;
            else         os[d - 256] = val;
        }
    }
}

// ---------------- fallback (R2 kernel): used only if ws is too small ----------------
#define FKSTRIDE 200
#define FVSTRIDE 72
__global__ __launch_bounds__(256, 2)
void geoattn_fallback(const float* __restrict__ q_mv, const float* __restrict__ k_mv,
                      const float* __restrict__ v_mv, const float* __restrict__ q_s,
                      const float* __restrict__ k_s, const float* __restrict__ v_s,
                      const float* __restrict__ logw, float* __restrict__ out)
{
    constexpr int IPIDX[8] = {0, 2, 3, 4, 8, 9, 10, 14};
    __shared__ __align__(16) _Float16 lds_k[64 * FKSTRIDE];
    __shared__ __align__(16) _Float16 lds_vt[288 * FVSTRIDE];
    __shared__ __align__(16) _Float16 lds_p[4 * 16 * FVSTRIDE];

    const int bid  = blockIdx.x;
    const int head = (bid & 7) | ((bid >> 8) << 3);
    const int qt   = (bid >> 3) & 31;
    const int h    = head & 7;
    const int tid  = threadIdx.x;
    const int w    = tid >> 6;
    const int lane = tid & 63;
    const int lr   = lane & 15;
    const int lg   = lane >> 4;
    const size_t rowbase = (size_t)head * NSEQ;
    const int q0 = qt * 64;
    const float scale = 0.07216878364870323f;

    f16x8 qf[6];
    {
        const int qrow = q0 + w * 16 + lr;
        const float* qmv = q_mv + (rowbase + qrow) * 256;
        const float* qs  = q_s  + (rowbase + qrow) * 32;
        #pragma unroll
        for (int c = 0; c < 4; ++c) {
            const int cmv = 4 * c + lg;
            const float wgt = __expf(logw[h * 16 + cmv]) * scale;
            const float* p = qmv + cmv * 16;
            #pragma unroll
            for (int i = 0; i < 8; ++i) qf[c][i] = (_Float16)(p[IPIDX[i]] * wgt);
        }
        const f32x4* p4 = (const f32x4*)(qs + lg * 8);
        f32x4 a = p4[0], b = p4[1];
        #pragma unroll
        for (int i = 0; i < 8; ++i) {
            float x = (i < 4) ? a[i & 3] : b[i & 3];
            qf[4][i] = (_Float16)(scale * x / (x * x + 1e-3f));
            qf[5][i] = (_Float16)(scale * x);
        }
    }
    f32x4 acc[18];
    #pragma unroll
    for (int dt = 0; dt < 18; ++dt) acc[dt] = f32x4{0.f, 0.f, 0.f, 0.f};
    float mrun[4] = {-1e30f, -1e30f, -1e30f, -1e30f};
    float lrun[4] = {0.f, 0.f, 0.f, 0.f};

    for (int kt = 0; kt < 32; ++kt) {
        const int j0 = kt * 64;
        __syncthreads();
        #pragma unroll
        for (int rep = 0; rep < 6; ++rep) {
            const int t = rep * 256 + tid;
            const int j = t & 63, oct = t >> 6;
            const size_t krow = rowbase + j0 + j;
            float v[8];
            if (oct < 16) {
                const float* p = k_mv + (krow * 16 + oct) * 16;
                #pragma unroll
                for (int i = 0; i < 8; ++i) v[i] = p[IPIDX[i]];
            } else if (oct < 20) {
                const f32x4* p4 = (const f32x4*)(k_s + krow * 32 + (oct - 16) * 8);
                f32x4 a = p4[0], b = p4[1];
                #pragma unroll
                for (int i = 0; i < 8; ++i) {
                    float x = (i < 4) ? a[i & 3] : b[i & 3];
                    v[i] = x / (x * x + 1e-3f);
                }
            } else {
                const f32x4* p4 = (const f32x4*)(k_s + krow * 32 + (oct - 20) * 8);
                f32x4 a = p4[0], b = p4[1];
                #pragma unroll
                for (int i = 0; i < 8; ++i) v[i] = (i < 4) ? a[i & 3] : b[i & 3];
            }
            f16x8 o;
            #pragma unroll
            for (int i = 0; i < 8; ++i) o[i] = (_Float16)v[i];
            *(f16x8*)(&lds_k[j * FKSTRIDE + oct * 8]) = o;
        }
        #pragma unroll
        for (int rep = 0; rep < 9; ++rep) {
            const int t = rep * 256 + tid;
            const int j = t & 63, oct = t >> 6;
            const size_t vrow = rowbase + j0 + j;
            const float* src = (oct < 32) ? (v_mv + vrow * 256 + oct * 8)
                                          : (v_s  + vrow * 32 + (oct - 32) * 8);
            const f32x4* p4 = (const f32x4*)src;
            f32x4 a = p4[0], b = p4[1];
            const int d0 = oct * 8;
            #pragma unroll
            for (int i = 0; i < 8; ++i)
                lds_vt[(d0 + i) * FVSTRIDE + j] = (_Float16)((i < 4) ? a[i & 3] : b[i & 3]);
        }
        __syncthreads();
        f32x4 sacc[4];
        #pragma unroll
        for (int nt = 0; nt < 4; ++nt) {
            sacc[nt] = f32x4{0.f, 0.f, 0.f, 0.f};
            #pragma unroll
            for (int c = 0; c < 6; ++c) {
                f16x8 kf = *(const f16x8*)(&lds_k[(lr + 16 * nt) * FKSTRIDE + 32 * c + lg * 8]);
                sacc[nt] = __builtin_amdgcn_mfma_f32_16x16x32_f16(qf[c], kf, sacc[nt], 0, 0, 0);
            }
        }
        float tmax[4], alpha[4];
        #pragma unroll
        for (int r = 0; r < 4; ++r) {
            float t0 = fmaxf(fmaxf(sacc[0][r], sacc[1][r]), fmaxf(sacc[2][r], sacc[3][r]));
            #pragma unroll
            for (int mm = 1; mm < 16; mm <<= 1) t0 = fmaxf(t0, __shfl_xor(t0, mm));
            tmax[r] = t0;
        }
        bool need = false;
        #pragma unroll
        for (int r = 0; r < 4; ++r) {
            float mnew = fmaxf(mrun[r], tmax[r]);
            need = need || (tmax[r] > mrun[r]);
            alpha[r] = __expf(mrun[r] - mnew);
            mrun[r] = mnew;
        }
        float pvv[4][4];
        float psum[4] = {0.f, 0.f, 0.f, 0.f};
        #pragma unroll
        for (int nt = 0; nt < 4; ++nt)
            #pragma unroll
            for (int r = 0; r < 4; ++r) {
                float p = __expf(sacc[nt][r] - mrun[r]);
                pvv[nt][r] = p;
                psum[r] += p;
            }
        #pragma unroll
        for (int r = 0; r < 4; ++r) {
            float s = psum[r];
            #pragma unroll
            for (int mm = 1; mm < 16; mm <<= 1) s += __shfl_xor(s, mm);
            lrun[r] = lrun[r] * alpha[r] + s;
        }
        if (__ballot(need)) {
            #pragma unroll
            for (int dt = 0; dt < 18; ++dt)
                #pragma unroll
                for (int r = 0; r < 4; ++r) acc[dt][r] *= alpha[r];
        }
        _Float16* pbf = &lds_p[w * 16 * FVSTRIDE];
        #pragma unroll
        for (int nt = 0; nt < 4; ++nt)
            #pragma unroll
            for (int r = 0; r < 4; ++r)
                pbf[(lg * 4 + r) * FVSTRIDE + lr + 16 * nt] = (_Float16)pvv[nt][r];
        #pragma unroll
        for (int ch = 0; ch < 2; ++ch) {
            f16x8 pf = *(const f16x8*)(&pbf[lr * FVSTRIDE + 32 * ch + lg * 8]);
            #pragma unroll
            for (int dt = 0; dt < 18; ++dt) {
                f16x8 vf = *(const f16x8*)(&lds_vt[(lr + 16 * dt) * FVSTRIDE + 32 * ch + lg * 8]);
                acc[dt] = __builtin_amdgcn_mfma_f32_16x16x32_f16(pf, vf, acc[dt], 0, 0, 0);
            }
        }
    }
    const int orow = q0 + w * 16 + lg * 4;
    #pragma unroll
    for (int r = 0; r < 4; ++r) {
        const float inv = 1.0f / lrun[r];
        float* omv = out + (rowbase + orow + r) * 256;
        float* os  = out + 8388608ull + (rowbase + orow + r) * 32;
        #pragma unroll
        for (int dt = 0; dt < 18; ++dt) {
            const int d = lr + 16 * dt;
            const float val = acc[dt][r] * inv;
            if (d < 256) omv[d] = val;
            else         os[d - 256] = val;
        }
    }
}

extern "C" void kernel_launch(void* const* d_in, const int* in_sizes, int n_in,
                              void* d_out, int out_size, void* d_ws, size_t ws_size,
                              hipStream_t stream) {
    (void)in_sizes; (void)n_in; (void)out_size;
    const float* q_mv = (const float*)d_in[0];
    const float* k_mv = (const float*)d_in[1];
    const float* v_mv = (const float*)d_in[2];
    const float* q_s  = (const float*)d_in[3];
    const float* k_s  = (const float*)d_in[4];
    const float* v_s  = (const float*)d_in[5];
    const float* logw = (const float*)d_in[6];
    float* out = (float*)d_out;

    if (ws_size >= WS_NEED) {
        unsigned char* ws = (unsigned char*)d_ws;
        prep_kf<<<dim3(512), dim3(256), 0, stream>>>(k_mv, k_s, ws);
        prep_vt<<<dim3(512), dim3(256), 0, stream>>>(v_mv, v_s, ws);
        geoattn_main<<<dim3(512), dim3(256), 0, stream>>>(q_mv, q_s, logw, ws, out);
    } else {
        geoattn_fallback<<<dim3(512), dim3(256), 0, stream>>>(q_mv, k_mv, v_mv, q_s, k_s, v_s, logw, out);
    }
}

// Round 14
// 119.765 us; speedup vs baseline: 2.6033x; 2.6033x over previous
//
#include <hip/hip_runtime.h>

typedef float f32x4 __attribute__((ext_vector_type(4)));
typedef _Float16 f16x8 __attribute__((ext_vector_type(8)));
typedef _Float16 f16x4 __attribute__((ext_vector_type(4)));

#define NSEQ 2048
#define KVBLK 64
#define NITER (NSEQ / KVBLK)        // 32
#define KFBYTES (KVBLK * 384)       // 24576 = 6*4096  (64 keys x 192 dims f16)
#define VTBYTES (288 * 2 * KVBLK)   // 36864 = 9*4096  (288 dims x 64 keys f16)
#define TILEB (KFBYTES + VTBYTES)   // 61440 = 15*4096
#define KFOFF 0
#define VTOFF KFBYTES
#define PSTRIDE 72                  // f16 per P row (64 + 8 pad) -> 144B
#define WS_NEED (16ull * NITER * TILEB)   // 31,457,280 B

#define SCALE_L2E 0.10411754f       // log2(e)/sqrt(192): softmax in exp2 domain
#define DEFER_THR 11.0f             // defer-max threshold (log2 units); P <= 2^11 ok in f16

__device__ __forceinline__ void async_copy16(const void* g, void* l) {
    __builtin_amdgcn_global_load_lds((const __attribute__((address_space(1))) unsigned int*)g,
                                     (__attribute__((address_space(3))) unsigned int*)l, 16, 0, 0);
}

// ---------------- fused pre-pass: one launch, two bodies ----------------
// blocks 0..511:    k features -> swizzled tile  (j*384 + d*2) ^ ((j&7)<<4)
// blocks 512..1023: V^T        -> swizzled tile  (d*128 + j*2) ^ ((d&7)<<4)
__global__ __launch_bounds__(256)
void prep_all(const float* __restrict__ k_mv, const float* __restrict__ k_s,
              const float* __restrict__ v_mv, const float* __restrict__ v_s,
              unsigned char* __restrict__ ws)
{
    constexpr int IPIDX[8] = {0, 2, 3, 4, 8, 9, 10, 14};
    const int tid = threadIdx.x;
    if (blockIdx.x < 512) {
        const int bid = blockIdx.x;
        const int head = bid >> 5, kt = bid & 31;
        unsigned char* tb = ws + (size_t)(head * NITER + kt) * TILEB + KFOFF;
        #pragma unroll
        for (int rep = 0; rep < 6; ++rep) {
            const int t = rep * 256 + tid;
            const int j = t & 63, oct = t >> 6;       // oct in [0,24)
            const size_t row = (size_t)head * NSEQ + kt * KVBLK + j;
            float v[8];
            if (oct < 16) {                            // IP gather, cmv = oct
                const float* p = k_mv + (row * 16 + oct) * 16;
                #pragma unroll
                for (int i = 0; i < 8; ++i) v[i] = p[IPIDX[i]];
            } else if (oct < 20) {                     // normalizer(k_s)
                const f32x4* p4 = (const f32x4*)(k_s + row * 32 + (oct - 16) * 8);
                f32x4 a = p4[0], b = p4[1];
                #pragma unroll
                for (int i = 0; i < 8; ++i) {
                    float x = (i < 4) ? a[i & 3] : b[i & 3];
                    v[i] = x / (x * x + 1e-3f);
                }
            } else {                                   // plain k_s
                const f32x4* p4 = (const f32x4*)(k_s + row * 32 + (oct - 20) * 8);
                f32x4 a = p4[0], b = p4[1];
                #pragma unroll
                for (int i = 0; i < 8; ++i) v[i] = (i < 4) ? a[i & 3] : b[i & 3];
            }
            f16x8 o;
            #pragma unroll
            for (int i = 0; i < 8; ++i) o[i] = (_Float16)v[i];
            *(f16x8*)(tb + ((j * 384 + oct * 16) ^ ((j & 7) << 4))) = o;
        }
    } else {
        const int bid = blockIdx.x - 512;
        const int head = bid >> 5, kt = bid & 31;
        unsigned char* tb = ws + (size_t)(head * NITER + kt) * TILEB + VTOFF;
        const size_t row0 = (size_t)head * NSEQ + kt * KVBLK;
        {
            const int d = tid;                         // 0..255 from v_mv
            float val[KVBLK];
            #pragma unroll
            for (int j = 0; j < KVBLK; ++j) val[j] = v_mv[(row0 + j) * 256 + d];
            #pragma unroll
            for (int jg = 0; jg < 8; ++jg) {
                f16x8 o;
                #pragma unroll
                for (int i = 0; i < 8; ++i) o[i] = (_Float16)val[jg * 8 + i];
                *(f16x8*)(tb + ((d * 128 + jg * 16) ^ ((d & 7) << 4))) = o;
            }
        }
        if (tid < 32) {                                // d = 256..287 from v_s
            const int d = 256 + tid;
            float val[KVBLK];
            #pragma unroll
            for (int j = 0; j < KVBLK; ++j) val[j] = v_s[(row0 + j) * 32 + tid];
            #pragma unroll
            for (int jg = 0; jg < 8; ++jg) {
                f16x8 o;
                #pragma unroll
                for (int i = 0; i < 8; ++i) o[i] = (_Float16)val[jg * 8 + i];
                *(f16x8*)(tb + ((d * 128 + jg * 16) ^ ((d & 7) << 4))) = o;
            }
        }
    }
}

// ---- main (R11, best measured: 116 µs): 512 blocks x 256 threads (4 waves),
// 2 de-phased blocks/CU. Wave owns 16 q-rows end-to-end; P wave-private;
// single-buffered tile; 2 barriers/iter. ----
__global__ __launch_bounds__(256, 2)
void geoattn_main(const float* __restrict__ q_mv, const float* __restrict__ q_s,
                  const float* __restrict__ logw, const unsigned char* __restrict__ ws,
                  float* __restrict__ out)
{
    constexpr int IPIDX[8] = {0, 2, 3, 4, 8, 9, 10, 14};
    __shared__ __align__(16) unsigned char lbuf[TILEB];          // single buffer
    __shared__ __align__(16) _Float16 P_all[4][16 * PSTRIDE];    // per-wave private

    const int bid  = blockIdx.x;                       // 512 blocks
    const int head = (bid & 7) | ((bid >> 8) << 3);    // same-head blocks share an XCD
    const int qt   = (bid >> 3) & 31;
    const int h    = head & 7;

    const int tid  = threadIdx.x;
    const int w    = tid >> 6;       // 0..3
    const int lane = tid & 63;
    const int lr   = lane & 15;
    const int lg   = lane >> 4;

    const size_t rowbase = (size_t)head * NSEQ;
    const int q0 = qt * 64;
    const unsigned char* wsh = ws + (size_t)head * NITER * TILEB;

    // prologue: tile-0 DMA (15 chunks/thread exactly) before the Q build
    #pragma unroll
    for (int c = 0; c < 15; ++c)
        async_copy16(wsh + c * 4096 + tid * 16, &lbuf[c * 4096 + tid * 16]);

    // ---- Q fragment for own 16 rows (B-operand: col=lr=q-row, k=lg*8+i+32c) ----
    f16x8 qf[6];
    {
        const int qrow = q0 + w * 16 + lr;
        const float* qmv = q_mv + (rowbase + qrow) * 256;
        const float* qs  = q_s  + (rowbase + qrow) * 32;
        #pragma unroll
        for (int c = 0; c < 4; ++c) {
            const int cmv = 4 * c + lg;
            const float wgt = __expf(logw[h * 16 + cmv]) * SCALE_L2E;
            const float* p = qmv + cmv * 16;
            #pragma unroll
            for (int i = 0; i < 8; ++i)
                qf[c][i] = (_Float16)(p[IPIDX[i]] * wgt);
        }
        const f32x4* p4 = (const f32x4*)(qs + lg * 8);
        f32x4 a = p4[0], b = p4[1];
        #pragma unroll
        for (int i = 0; i < 8; ++i) {
            float x = (i < 4) ? a[i & 3] : b[i & 3];
            qf[4][i] = (_Float16)(SCALE_L2E * x / (x * x + 1e-3f));
            qf[5][i] = (_Float16)(SCALE_L2E * x);
        }
    }

    f32x4 acc[18];                    // own 16 rows x 288 dims
    #pragma unroll
    for (int dt = 0; dt < 18; ++dt) acc[dt] = f32x4{0.f, 0.f, 0.f, 0.f};
    float mrun = -1e30f, lrun = 0.f;  // lane owns q-row (w*16 + lr)

    _Float16* pb = &P_all[w][0];

    // tile-0 ready
    asm volatile("s_waitcnt vmcnt(0)" ::: "memory");
    __builtin_amdgcn_s_barrier();
    asm volatile("" ::: "memory");

    for (int kt = 0; kt < NITER; ++kt) {
        // ---- S^T = K Q : lane holds P-row of q-row lr across 4 key groups ----
        f32x4 sacc[4];
        #pragma unroll
        for (int jt = 0; jt < 4; ++jt) sacc[jt] = f32x4{0.f, 0.f, 0.f, 0.f};
        __builtin_amdgcn_s_setprio(1);
        #pragma unroll
        for (int jt = 0; jt < 4; ++jt) {
            const int j = jt * 16 + lr;                 // key row
            #pragma unroll
            for (int c = 0; c < 6; ++c) {
                f16x8 kf = *(const f16x8*)(lbuf + KFOFF +
                            ((j * 384 + c * 64 + lg * 16) ^ ((lr & 7) << 4)));
                sacc[jt] = __builtin_amdgcn_mfma_f32_16x16x32_f16(kf, qf[c], sacc[jt], 0, 0, 0);
            }
        }
        __builtin_amdgcn_s_setprio(0);

        // ---- softmax (exp2 domain, defer-max) for own 16 rows ----
        float mloc;
        {
            float t0 = fmaxf(fmaxf(sacc[0][0], sacc[0][1]), fmaxf(sacc[0][2], sacc[0][3]));
            #pragma unroll
            for (int jt = 1; jt < 4; ++jt) {
                float t1 = fmaxf(fmaxf(sacc[jt][0], sacc[jt][1]), fmaxf(sacc[jt][2], sacc[jt][3]));
                t0 = fmaxf(t0, t1);
            }
            t0 = fmaxf(t0, __shfl_xor(t0, 16));
            t0 = fmaxf(t0, __shfl_xor(t0, 32));
            mloc = t0;
        }
        const bool need = (mloc > mrun + DEFER_THR);
        const float mnew = need ? mloc : mrun;
        const float alpha = exp2f(mrun - mnew);         // 1.0 when !need; 0 on first tile
        mrun = mnew;
        if (__ballot(need)) {                           // rare: redistribute alpha to acc rows
            float ar[4];
            #pragma unroll
            for (int r = 0; r < 4; ++r) ar[r] = __shfl(alpha, lg * 4 + r, 16);
            #pragma unroll
            for (int dt = 0; dt < 18; ++dt)
                #pragma unroll
                for (int r = 0; r < 4; ++r) acc[dt][r] *= ar[r];
            lrun *= alpha;
        }
        float ps = 0.f;
        #pragma unroll
        for (int jt = 0; jt < 4; ++jt) {
            f16x4 pk;
            #pragma unroll
            for (int r = 0; r < 4; ++r) {
                const float p = exp2f(sacc[jt][r] - mrun);
                ps += p;
                pk[r] = (_Float16)p;
            }
            *(f16x4*)(&pb[lr * PSTRIDE + jt * 16 + lg * 4]) = pk;
        }
        ps += __shfl_xor(ps, 16);
        ps += __shfl_xor(ps, 32);
        lrun += ps;

        // ---- O += P V : own P (same-wave LDS, lgkmcnt-ordered, NO barrier) ----
        f16x8 pf0 = *(const f16x8*)(&pb[lr * PSTRIDE + lg * 8]);        // keys 0..31
        f16x8 pf1 = *(const f16x8*)(&pb[lr * PSTRIDE + 32 + lg * 8]);   // keys 32..63
        __builtin_amdgcn_s_setprio(1);
        #pragma unroll
        for (int dt = 0; dt < 18; ++dt) {
            const int d = dt * 16 + lr;
            const int vb = VTOFF + d * 128 + lg * 16;
            f16x8 vf0 = *(const f16x8*)(lbuf + ((vb) ^ ((d & 7) << 4)));
            f16x8 vf1 = *(const f16x8*)(lbuf + ((vb + 64) ^ ((d & 7) << 4)));
            acc[dt] = __builtin_amdgcn_mfma_f32_16x16x32_f16(pf0, vf0, acc[dt], 0, 0, 0);
            acc[dt] = __builtin_amdgcn_mfma_f32_16x16x32_f16(pf1, vf1, acc[dt], 0, 0, 0);
        }
        __builtin_amdgcn_s_setprio(0);

        // ---- refill lbuf with tile kt+1 (single buffer; partner block covers wait) ----
        asm volatile("s_waitcnt lgkmcnt(0)" ::: "memory");
        __builtin_amdgcn_s_barrier();                   // all waves done reading tile kt
        asm volatile("" ::: "memory");
        if (kt < NITER - 1) {
            const unsigned char* src = wsh + (size_t)(kt + 1) * TILEB;
            #pragma unroll
            for (int c = 0; c < 15; ++c)
                async_copy16(src + c * 4096 + tid * 16, &lbuf[c * 4096 + tid * 16]);
            asm volatile("s_waitcnt vmcnt(0)" ::: "memory");
            __builtin_amdgcn_s_barrier();               // tile kt+1 ready
            asm volatile("" ::: "memory");
        }
    }

    // ---- epilogue: out = acc / l (l redistributed in-wave; no cross-wave state) ----
    #pragma unroll
    for (int r = 0; r < 4; ++r) {
        const float lv = __shfl(lrun, lg * 4 + r, 16);
        const float inv = 1.0f / lv;
        const int row = q0 + w * 16 + lg * 4 + r;
        float* omv = out + (rowbase + row) * 256;
        float* os  = out + 8388608ull + (rowbase + row) * 32;
        #pragma unroll
        for (int dt = 0; dt < 18; ++dt) {
            const int d = dt * 16 + lr;
            const float val = acc[dt][r] * inv;
            if (d < 256) omv[d] = val;
            else         os[d - 256] = val;
        }
    }
}

// ---------------- fallback (R2 kernel): used only if ws is too small ----------------
#define FKSTRIDE 200
#define FVSTRIDE 72
__global__ __launch_bounds__(256, 2)
void geoattn_fallback(const float* __restrict__ q_mv, const float* __restrict__ k_mv,
                      const float* __restrict__ v_mv, const float* __restrict__ q_s,
                      const float* __restrict__ k_s, const float* __restrict__ v_s,
                      const float* __restrict__ logw, float* __restrict__ out)
{
    constexpr int IPIDX[8] = {0, 2, 3, 4, 8, 9, 10, 14};
    __shared__ __align__(16) _Float16 lds_k[64 * FKSTRIDE];
    __shared__ __align__(16) _Float16 lds_vt[288 * FVSTRIDE];
    __shared__ __align__(16) _Float16 lds_p[4 * 16 * FVSTRIDE];

    const int bid  = blockIdx.x;
    const int head = (bid & 7) | ((bid >> 8) << 3);
    const int qt   = (bid >> 3) & 31;
    const int h    = head & 7;
    const int tid  = threadIdx.x;
    const int w    = tid >> 6;
    const int lane = tid & 63;
    const int lr   = lane & 15;
    const int lg   = lane >> 4;
    const size_t rowbase = (size_t)head * NSEQ;
    const int q0 = qt * 64;
    const float scale = 0.07216878364870323f;

    f16x8 qf[6];
    {
        const int qrow = q0 + w * 16 + lr;
        const float* qmv = q_mv + (rowbase + qrow) * 256;
        const float* qs  = q_s  + (rowbase + qrow) * 32;
        #pragma unroll
        for (int c = 0; c < 4; ++c) {
            const int cmv = 4 * c + lg;
            const float wgt = __expf(logw[h * 16 + cmv]) * scale;
            const float* p = qmv + cmv * 16;
            #pragma unroll
            for (int i = 0; i < 8; ++i) qf[c][i] = (_Float16)(p[IPIDX[i]] * wgt);
        }
        const f32x4* p4 = (const f32x4*)(qs + lg * 8);
        f32x4 a = p4[0], b = p4[1];
        #pragma unroll
        for (int i = 0; i < 8; ++i) {
            float x = (i < 4) ? a[i & 3] : b[i & 3];
            qf[4][i] = (_Float16)(scale * x / (x * x + 1e-3f));
            qf[5][i] = (_Float16)(scale * x);
        }
    }
    f32x4 acc[18];
    #pragma unroll
    for (int dt = 0; dt < 18; ++dt) acc[dt] = f32x4{0.f, 0.f, 0.f, 0.f};
    float mrun[4] = {-1e30f, -1e30f, -1e30f, -1e30f};
    float lrun[4] = {0.f, 0.f, 0.f, 0.f};

    for (int kt = 0; kt < 32; ++kt) {
        const int j0 = kt * 64;
        __syncthreads();
        #pragma unroll
        for (int rep = 0; rep < 6; ++rep) {
            const int t = rep * 256 + tid;
            const int j = t & 63, oct = t >> 6;
            const size_t krow = rowbase + j0 + j;
            float v[8];
            if (oct < 16) {
                const float* p = k_mv + (krow * 16 + oct) * 16;
                #pragma unroll
                for (int i = 0; i < 8; ++i) v[i] = p[IPIDX[i]];
            } else if (oct < 20) {
                const f32x4* p4 = (const f32x4*)(k_s + krow * 32 + (oct - 16) * 8);
                f32x4 a = p4[0], b = p4[1];
                #pragma unroll
                for (int i = 0; i < 8; ++i) {
                    float x = (i < 4) ? a[i & 3] : b[i & 3];
                    v[i] = x / (x * x + 1e-3f);
                }
            } else {
                const f32x4* p4 = (const f32x4*)(k_s + krow * 32 + (oct - 20) * 8);
                f32x4 a = p4[0], b = p4[1];
                #pragma unroll
                for (int i = 0; i < 8; ++i) v[i] = (i < 4) ? a[i & 3] : b[i & 3];
            }
            f16x8 o;
            #pragma unroll
            for (int i = 0; i < 8; ++i) o[i] = (_Float16)v[i];
            *(f16x8*)(&lds_k[j * FKSTRIDE + oct * 8]) = o;
        }
        #pragma unroll
        for (int rep = 0; rep < 9; ++rep) {
            const int t = rep * 256 + tid;
            const int j = t & 63, oct = t >> 6;
            const size_t vrow = rowbase + j0 + j;
            const float* src = (oct < 32) ? (v_mv + vrow * 256 + oct * 8)
                                          : (v_s  + vrow * 32 + (oct - 32) * 8);
            const f32x4* p4 = (const f32x4*)src;
            f32x4 a = p4[0], b = p4[1];
            const int d0 = oct * 8;
            #pragma unroll
            for (int i = 0; i < 8; ++i)
                lds_vt[(d0 + i) * FVSTRIDE + j] = (_Float16)((i < 4) ? a[i & 3] : b[i & 3]);
        }
        __syncthreads();
        f32x4 sacc[4];
        #pragma unroll
        for (int nt = 0; nt < 4; ++nt) {
            sacc[nt] = f32x4{0.f, 0.f, 0.f, 0.f};
            #pragma unroll
            for (int c = 0; c < 6; ++c) {
                f16x8 kf = *(const f16x8*)(&lds_k[(lr + 16 * nt) * FKSTRIDE + 32 * c + lg * 8]);
                sacc[nt] = __builtin_amdgcn_mfma_f32_16x16x32_f16(qf[c], kf, sacc[nt], 0, 0, 0);
            }
        }
        float tmax[4], alpha[4];
        #pragma unroll
        for (int r = 0; r < 4; ++r) {
            float t0 = fmaxf(fmaxf(sacc[0][r], sacc[1][r]), fmaxf(sacc[2][r], sacc[3][r]));
            #pragma unroll
            for (int mm = 1; mm < 16; mm <<= 1) t0 = fmaxf(t0, __shfl_xor(t0, mm));
            tmax[r] = t0;
        }
        bool need = false;
        #pragma unroll
        for (int r = 0; r < 4; ++r) {
            float mnew = fmaxf(mrun[r], tmax[r]);
            need = need || (tmax[r] > mrun[r]);
            alpha[r] = __expf(mrun[r] - mnew);
            mrun[r] = mnew;
        }
        float pvv[4][4];
        float psum[4] = {0.f, 0.f, 0.f, 0.f};
        #pragma unroll
        for (int nt = 0; nt < 4; ++nt)
            #pragma unroll
            for (int r = 0; r < 4; ++r) {
                float p = __expf(sacc[nt][r] - mrun[r]);
                pvv[nt][r] = p;
                psum[r] += p;
            }
        #pragma unroll
        for (int r = 0; r < 4; ++r) {
            float s = psum[r];
            #pragma unroll
            for (int mm = 1; mm < 16; mm <<= 1) s += __shfl_xor(s, mm);
            lrun[r] = lrun[r] * alpha[r] + s;
        }
        if (__ballot(need)) {
            #pragma unroll
            for (int dt = 0; dt < 18; ++dt)
                #pragma unroll
                for (int r = 0; r < 4; ++r) acc[dt][r] *= alpha[r];
        }
        _Float16* pbf = &lds_p[w * 16 * FVSTRIDE];
        #pragma unroll
        for (int nt = 0; nt < 4; ++nt)
            #pragma unroll
            for (int r = 0; r < 4; ++r)
                pbf[(lg * 4 + r) * FVSTRIDE + lr + 16 * nt] = (_Float16)pvv[nt][r];
        #pragma unroll
        for (int ch = 0; ch < 2; ++ch) {
            f16x8 pf = *(const f16x8*)(&pbf[lr * FVSTRIDE + 32 * ch + lg * 8]);
            #pragma unroll
            for (int dt = 0; dt < 18; ++dt) {
                f16x8 vf = *(const f16x8*)(&lds_vt[(lr + 16 * dt) * FVSTRIDE + 32 * ch + lg * 8]);
                acc[dt] = __builtin_amdgcn_mfma_f32_16x16x32_f16(pf, vf, acc[dt], 0, 0, 0);
            }
        }
    }
    const int orow = q0 + w * 16 + lg * 4;
    #pragma unroll
    for (int r = 0; r < 4; ++r) {
        const float inv = 1.0f / lrun[r];
        float* omv = out + (rowbase + orow + r) * 256;
        float* os  = out + 8388608ull + (rowbase + orow + r) * 32;
        #pragma unroll
        for (int dt = 0; dt < 18; ++dt) {
            const int d = lr + 16 * dt;
            const float val = acc[dt][r] * inv;
            if (d < 256) omv[d] = val;
            else         os[d - 256] = val;
        }
    }
}

extern "C" void kernel_launch(void* const* d_in, const int* in_sizes, int n_in,
                              void* d_out, int out_size, void* d_ws, size_t ws_size,
                              hipStream_t stream) {
    (void)in_sizes; (void)n_in; (void)out_size;
    const float* q_mv = (const float*)d_in[0];
    const float* k_mv = (const float*)d_in[1];
    const float* v_mv = (const float*)d_in[2];
    const float* q_s  = (const float*)d_in[3];
    const float* k_s  = (const float*)d_in[4];
    const float* v_s  = (const float*)d_in[5];
    const float* logw = (const float*)d_in[6];
    float* out = (float*)d_out;

    if (ws_size >= WS_NEED) {
        unsigned char* ws = (unsigned char*)d_ws;
        prep_all<<<dim3(1024), dim3(256), 0, stream>>>(k_mv, k_s, v_mv, v_s, ws);
        geoattn_main<<<dim3(512), dim3(256), 0, stream>>>(q_mv, q_s, logw, ws, out);
    } else {
        geoattn_fallback<<<dim3(512), dim3(256), 0, stream>>>(q_mv, k_mv, v_mv, q_s, k_s, v_s, logw, out);
    }
}